// Round 12
// baseline (118.466 us; speedup 1.0000x reference)
//
#include <hip/hip_runtime.h>
#include <hip/hip_bf16.h>

#define STATE 16
#define DNA_C 4
#define HID   128
#define FAN1  52
#define HH    256
#define WW    256
#define HW    (HH * WW)

typedef unsigned short u16;
typedef unsigned int   u32;
typedef short bf8 __attribute__((ext_vector_type(8)));
typedef float f32x4 __attribute__((ext_vector_type(4)));

__device__ __forceinline__ u32 pk(float a, float b) {
    __hip_bfloat162 t = __float22bfloat162_rn(make_float2(a, b));  // v_cvt_pk_bf16_f32
    union { __hip_bfloat162 h; u32 u; } c; c.h = t; return c.u;
}
__device__ __forceinline__ u16 f2bf(float f) {
    union { __hip_bfloat16 h; u16 u; } c; c.h = __float2bfloat16(f); return c.u;
}

// w1 [128][52] f32 -> bf16 [128][64] with k-permutation baked in:
// knew = 16w + t : t0-3 = x ch 4w+t, t4-7 = gx ch 4w+(t-4), t8-11 = gy ch 4w+(t-8),
//                  t12-15 = dna (w==0) else zero-pad.   w2 [16][128] -> bf16 plain.
__global__ void prep_weights(const float* __restrict__ w1, const float* __restrict__ w2,
                             u16* __restrict__ wb) {
    int i = blockIdx.x * 256 + threadIdx.x;   // 0..10239
    if (i < 128 * 64) {
        int r = i >> 6, knew = i & 63;
        int w = knew >> 4, t = knew & 15;
        float v = 0.f;
        if (t < 4)        v = w1[r * FAN1 + 4 * w + t];
        else if (t < 8)   v = w1[r * FAN1 + 16 + 4 * w + (t - 4)];
        else if (t < 12)  v = w1[r * FAN1 + 32 + 4 * w + (t - 8)];
        else if (w == 0)  v = w1[r * FAN1 + 48 + (t - 12)];
        wb[i] = f2bf(v);
    } else if (i < 128 * 64 + 16 * 128) {
        wb[i] = f2bf(w2[i - 128 * 64]);
    }
}

__global__ __launch_bounds__(256, 4) void update_net12(
    const float* __restrict__ x,    // [B,16,256,256]
    const float* __restrict__ dna,  // [B,4,256,256]
    const u16*   __restrict__ wb,   // permuted bf16 w1 [128][64], w2 [16][128]
    float* __restrict__ out)        // [B,16,256,256]
{
    // feat: [256 px][64 k] bf16, 128B rows, 16B chunks swizzled chunk ^= (px>>2)&7. 32 KB.
    // Feature phase is cross-wave (wave wv writes chunks 2wv,2wv+1 of ALL rows) -> one barrier.
    // After the barrier wave wv owns rows [wv*64, wv*64+64).
    // h [16 px][128 k] = 2048 u16 = 32 feat rows -> overlays the LOWER half (rows wv*64..+31):
    //   g4=0 rows read JIT in iteration 0 (before any h write, program order + in-order DS),
    //   g4=1 rows pre-read into 8 regs, g4=2,3 rows never overlaid.
    __shared__ __align__(16) u16 feat_lds[256 * 64];

    const int tid  = threadIdx.x;
    const int lane = tid & 63;
    const int wv   = tid >> 6;
    const int row  = blockIdx.x;
    const int b    = row >> 8;
    const int y    = row & 255;
    const bool ht  = (y > 0), hb = (y < HH - 1);   // block-uniform

    // ---- feature phase: wave wv -> channels 4wv..4wv+3, full row, 4 px/lane ----
    {
        const int px0 = lane * 4;
        const float* base = x + (((size_t)(b * STATE + 4 * wv)) * HH + y) * WW + px0;

        f32x4 xm[4], gx[4], gy[4];
        #pragma unroll
        for (int c = 0; c < 4; ++c) {
            const float* p = base + (size_t)c * HW;
            f32x4 m4 = *(const f32x4*)p;
            f32x4 t4 = {0.f,0.f,0.f,0.f}, b4 = {0.f,0.f,0.f,0.f};
            if (ht) t4 = *(const f32x4*)(p - WW);
            if (hb) b4 = *(const f32x4*)(p + WW);
            f32x4 cs, d;
            #pragma unroll
            for (int i = 0; i < 4; ++i) {
                cs[i] = fmaf(2.f, m4[i], t4[i] + b4[i]);   // colsum t+2m+b
                d[i]  = b4[i] - t4[i];
            }
            float csL = __shfl_up(cs[3], 1);
            float csR = __shfl_down(cs[0], 1);
            float dL  = __shfl_up(d[3], 1);
            float dR  = __shfl_down(d[0], 1);
            if (lane == 0)  { csL = 0.f; dL = 0.f; }       // image left border (zero pad)
            if (lane == 63) { csR = 0.f; dR = 0.f; }       // image right border
            xm[c] = m4;
            gx[c][0] = cs[1] - csL;   gx[c][1] = cs[2] - cs[0];
            gx[c][2] = cs[3] - cs[1]; gx[c][3] = csR - cs[2];
            gy[c][0] = fmaf(2.f, d[0], dL + d[1]);
            gy[c][1] = fmaf(2.f, d[1], d[0] + d[2]);
            gy[c][2] = fmaf(2.f, d[2], d[1] + d[3]);
            gy[c][3] = fmaf(2.f, d[3], d[2] + dR);
        }
        f32x4 dn[4] = {{0,0,0,0},{0,0,0,0},{0,0,0,0},{0,0,0,0}};
        if (wv == 0) {
            #pragma unroll
            for (int dc = 0; dc < 4; ++dc)
                dn[dc] = *(const f32x4*)(dna + (((size_t)(b * DNA_C + dc)) * HH + y) * WW + px0);
        }
        const int s = lane & 7;   // (px>>2)&7 for all 4 px of this lane
        #pragma unroll
        for (int i = 0; i < 4; ++i) {
            u16* rowp = &feat_lds[(px0 + i) * 64];
            uint4 c0 = make_uint4(pk(xm[0][i], xm[1][i]), pk(xm[2][i], xm[3][i]),
                                  pk(gx[0][i], gx[1][i]), pk(gx[2][i], gx[3][i]));
            uint4 c1 = make_uint4(pk(gy[0][i], gy[1][i]), pk(gy[2][i], gy[3][i]),
                                  pk(dn[0][i], dn[1][i]), pk(dn[2][i], dn[3][i]));
            *(uint4*)&rowp[8 * ((2 * wv)     ^ s)] = c0;   // knew 16wv..+7  : x | gx
            *(uint4*)&rowp[8 * ((2 * wv + 1) ^ s)] = c1;   // knew 16wv+8..15: gy | dna/pad
        }
    }

    // Phase separator: keep the weight-fragment loads from being hoisted into the
    // feature phase (register peaks become max(), not sum).
    __builtin_amdgcn_sched_barrier(0);

    const int fj  = lane & 15;   // A-row / B-col / D-col
    const int fg  = lane >> 4;   // k-group (A/B), row-group (D)
    const int sfj = fj & 7;      // h-buffer swizzle
    const int f4  = fj >> 2;     // feat read swizzle base: sg(g4) = (4*g4 + f4) & 7

    // ---- weight fragments: global bf16 -> registers ----
    const u16* w1b = wb;             // [128][64] (k-permuted)
    const u16* w2b = wb + 128 * 64;  // [16][128]
    bf8 a1[8][2];
    #pragma unroll
    for (int m = 0; m < 8; ++m) {
        #pragma unroll
        for (int kt = 0; kt < 2; ++kt)
            a1[m][kt] = *(const bf8*)&w1b[(16 * m + fj) * 64 + 32 * kt + 8 * fg];
    }
    bf8 a2[4];
    #pragma unroll
    for (int kt = 0; kt < 4; ++kt)
        a2[kt] = *(const bf8*)&w2b[fj * 128 + 32 * kt + 8 * fg];

    __syncthreads();   // feature phase is cross-wave

    // ---- g4=1 pre-read (its rows 16..31 are overlaid by g4=0's h writes) ----
    bf8 p10, p11;
    {
        const int r1 = wv * 64 + 16 + fj;   const int s1 = (4 + f4) & 7;  // (1*4+f4)&7
        p10 = *(const bf8*)&feat_lds[r1 * 64 + 8 * ((0 + fg) ^ s1)];
        p11 = *(const bf8*)&feat_lds[r1 * 64 + 8 * ((4 + fg) ^ s1)];
    }

    u16* hwv = &feat_lds[wv * 4096];   // h [16 px][128 k] over rows wv*64 .. +31

    #pragma unroll
    for (int g4 = 0; g4 < 4; ++g4) {
        bf8 b0, b1;
        if (g4 == 1) { b0 = p10; b1 = p11; }
        else {
            // g4=0: JIT read of rows 0..15 in iteration 0, before any h write
            // (program order + in-order per-wave DS). g4=2,3: rows never overlaid.
            const int r  = wv * 64 + g4 * 16 + fj;
            const int sg = (4 * g4 + f4) & 7;
            b0 = *(const bf8*)&feat_lds[r * 64 + 8 * ((0 + fg) ^ sg)];
            b1 = *(const bf8*)&feat_lds[r * 64 + 8 * ((4 + fg) ^ sg)];
        }

        // ---- layer 1 in two m-halves (16-reg accumulator) ----
        #pragma unroll
        for (int mh = 0; mh < 2; ++mh) {
            f32x4 hc[4];
            #pragma unroll
            for (int mm = 0; mm < 4; ++mm) {
                const int m = mh * 4 + mm;
                f32x4 z = {0.f, 0.f, 0.f, 0.f};
                z = __builtin_amdgcn_mfma_f32_16x16x32_bf16(a1[m][0], b0, z, 0, 0, 0);
                hc[mm] = __builtin_amdgcn_mfma_f32_16x16x32_bf16(a1[m][1], b1, z, 0, 0, 0);
            }
            #pragma unroll
            for (int mm = 0; mm < 4; ++mm) {
                const int m = mh * 4 + mm;
                float h0 = fmaxf(hc[mm][0], 0.f), h1 = fmaxf(hc[mm][1], 0.f);
                float h2 = fmaxf(hc[mm][2], 0.f), h3 = fmaxf(hc[mm][3], 0.f);
                *(uint2*)&hwv[fj * 128 + 8 * ((2 * m + (fg >> 1)) ^ sfj) + 4 * (fg & 1)] =
                    make_uint2(pk(h0, h1), pk(h2, h3));
            }
        }

        // layer 2: h read-back (in-order DS; compiler inserts counted lgkmcnt)
        f32x4 uacc = {0.f, 0.f, 0.f, 0.f};
        #pragma unroll
        for (int kt = 0; kt < 4; ++kt) {
            bf8 b2 = *(const bf8*)&hwv[fj * 128 + 8 * ((4 * kt + fg) ^ sfj)];
            uacc = __builtin_amdgcn_mfma_f32_16x16x32_bf16(a2[kt], b2, uacc, 0, 0, 0);
        }

        const int xo = wv * 64 + g4 * 16 + fj;
        float* po = out + (((size_t)(b * STATE + 4 * fg)) * HH + y) * WW + xo;
        #pragma unroll
        for (int rr = 0; rr < 4; ++rr)
            po[(size_t)rr * HW] = uacc[rr];
    }
}

extern "C" void kernel_launch(void* const* d_in, const int* in_sizes, int n_in,
                              void* d_out, int out_size, void* d_ws, size_t ws_size,
                              hipStream_t stream) {
    const float* x   = (const float*)d_in[0];
    const float* dna = (const float*)d_in[1];
    const float* w1  = (const float*)d_in[2];
    const float* w2  = (const float*)d_in[3];
    float* out = (float*)d_out;
    u16* wb = (u16*)d_ws;   // 10240 u16 = 20 KB

    prep_weights<<<dim3(40), dim3(256), 0, stream>>>(w1, w2, wb);

    const int B = in_sizes[0] / (STATE * HH * WW);   // 16
    update_net12<<<dim3(B * HH), dim3(256), 0, stream>>>(x, dna, wb, out);
}

// Round 13
// 75.441 us; speedup vs baseline: 1.5703x; 1.5703x over previous
//
#include <hip/hip_runtime.h>
#include <hip/hip_bf16.h>

#define STATE 16
#define DNA_C 4
#define HID   128
#define FAN1  52
#define HH    256
#define WW    256
#define HW    (HH * WW)

typedef unsigned short u16;
typedef unsigned int   u32;
typedef short bf8 __attribute__((ext_vector_type(8)));
typedef float f32x4 __attribute__((ext_vector_type(4)));

__device__ __forceinline__ u32 pk(float a, float b) {
    __hip_bfloat162 t = __float22bfloat162_rn(make_float2(a, b));  // v_cvt_pk_bf16_f32
    union { __hip_bfloat162 h; u32 u; } c; c.h = t; return c.u;
}
__device__ __forceinline__ u16 f2bf(float f) {
    union { __hip_bfloat16 h; u16 u; } c; c.h = __float2bfloat16(f); return c.u;
}

// w1 [128][52] f32 -> bf16 [128][64], DOUBLY permuted:
//  * k-permutation (feature interleave): knew = 16w + t with t0-3 = x ch4w.., t4-7 = gx,
//    t8-11 = gy, t12-15 = dna(w==0)/pad — matches the feature-phase LDS layout.
//  * M-permutation (hidden-unit reorder): physical row p = 16m+4g+r computes TRUE hidden
//    unit H(p) = 32*(m>>1) + 8g + 4*(m&1) + r.  With this bijection, the L1 D-fragment
//    each lane (fj,fg) holds IS its L2 B-fragment (k = 32kt+8fg+e, same col fj) -> the
//    h exchange needs no LDS and no shuffles at all.
// w2 [16][128] -> bf16 plain (true hidden ordering).
__global__ void prep_weights(const float* __restrict__ w1, const float* __restrict__ w2,
                             u16* __restrict__ wb) {
    int i = blockIdx.x * 256 + threadIdx.x;   // 0..10239
    if (i < 128 * 64) {
        int p = i >> 6, knew = i & 63;
        int m = p >> 4, g = (p >> 2) & 3, r = p & 3;
        int hrow = 32 * (m >> 1) + 8 * g + 4 * (m & 1) + r;   // true hidden row at physical p
        int w = knew >> 4, t = knew & 15;
        float v = 0.f;
        if (t < 4)        v = w1[hrow * FAN1 + 4 * w + t];
        else if (t < 8)   v = w1[hrow * FAN1 + 16 + 4 * w + (t - 4)];
        else if (t < 12)  v = w1[hrow * FAN1 + 32 + 4 * w + (t - 8)];
        else if (w == 0)  v = w1[hrow * FAN1 + 48 + (t - 12)];
        wb[i] = f2bf(v);
    } else if (i < 128 * 64 + 16 * 128) {
        wb[i] = f2bf(w2[i - 128 * 64]);
    }
}

__global__ __launch_bounds__(256, 3) void update_net13(
    const float* __restrict__ x,    // [B,16,256,256]
    const float* __restrict__ dna,  // [B,4,256,256]
    const u16*   __restrict__ wb,   // permuted bf16 w1 [128][64], w2 [16][128]
    float* __restrict__ out)        // [B,16,256,256]
{
    // feat: [256 px][64 k] bf16, 128B rows, 16B chunks swizzled chunk ^= (px>>2)&7. 32 KB.
    // Feature phase cross-wave (wave wv writes chunks 2wv,2wv+1 of ALL rows) -> one barrier.
    // feat_lds is WRITE-ONCE, READ-ONLY afterwards: no h overlay, no aliasing hazards,
    // the 4 g4 chains are fully independent and freely schedulable.
    __shared__ __align__(16) u16 feat_lds[256 * 64];

    const int tid  = threadIdx.x;
    const int lane = tid & 63;
    const int wv   = tid >> 6;
    const int row  = blockIdx.x;
    const int b    = row >> 8;
    const int y    = row & 255;
    const bool ht  = (y > 0), hb = (y < HH - 1);   // block-uniform

    // ---- feature phase: wave wv -> channels 4wv..4wv+3, full row, 4 px/lane ----
    {
        const int px0 = lane * 4;
        const float* base = x + (((size_t)(b * STATE + 4 * wv)) * HH + y) * WW + px0;

        f32x4 xm[4], gx[4], gy[4];
        #pragma unroll
        for (int c = 0; c < 4; ++c) {
            const float* p = base + (size_t)c * HW;
            f32x4 m4 = *(const f32x4*)p;
            f32x4 t4 = {0.f,0.f,0.f,0.f}, b4 = {0.f,0.f,0.f,0.f};
            if (ht) t4 = *(const f32x4*)(p - WW);
            if (hb) b4 = *(const f32x4*)(p + WW);
            f32x4 cs, d;
            #pragma unroll
            for (int i = 0; i < 4; ++i) {
                cs[i] = fmaf(2.f, m4[i], t4[i] + b4[i]);   // colsum t+2m+b
                d[i]  = b4[i] - t4[i];
            }
            float csL = __shfl_up(cs[3], 1);
            float csR = __shfl_down(cs[0], 1);
            float dL  = __shfl_up(d[3], 1);
            float dR  = __shfl_down(d[0], 1);
            if (lane == 0)  { csL = 0.f; dL = 0.f; }       // image left border (zero pad)
            if (lane == 63) { csR = 0.f; dR = 0.f; }       // image right border
            xm[c] = m4;
            gx[c][0] = cs[1] - csL;   gx[c][1] = cs[2] - cs[0];
            gx[c][2] = cs[3] - cs[1]; gx[c][3] = csR - cs[2];
            gy[c][0] = fmaf(2.f, d[0], dL + d[1]);
            gy[c][1] = fmaf(2.f, d[1], d[0] + d[2]);
            gy[c][2] = fmaf(2.f, d[2], d[1] + d[3]);
            gy[c][3] = fmaf(2.f, d[3], d[2] + dR);
        }
        f32x4 dn[4] = {{0,0,0,0},{0,0,0,0},{0,0,0,0},{0,0,0,0}};
        if (wv == 0) {
            #pragma unroll
            for (int dc = 0; dc < 4; ++dc)
                dn[dc] = *(const f32x4*)(dna + (((size_t)(b * DNA_C + dc)) * HH + y) * WW + px0);
        }
        const int s = lane & 7;   // (px>>2)&7 for all 4 px of this lane
        #pragma unroll
        for (int i = 0; i < 4; ++i) {
            u16* rowp = &feat_lds[(px0 + i) * 64];
            uint4 c0 = make_uint4(pk(xm[0][i], xm[1][i]), pk(xm[2][i], xm[3][i]),
                                  pk(gx[0][i], gx[1][i]), pk(gx[2][i], gx[3][i]));
            uint4 c1 = make_uint4(pk(gy[0][i], gy[1][i]), pk(gy[2][i], gy[3][i]),
                                  pk(dn[0][i], dn[1][i]), pk(dn[2][i], dn[3][i]));
            *(uint4*)&rowp[8 * ((2 * wv)     ^ s)] = c0;   // knew 16wv..+7  : x | gx
            *(uint4*)&rowp[8 * ((2 * wv + 1) ^ s)] = c1;   // knew 16wv+8..15: gy | dna/pad
        }
    }

    const int fj = lane & 15;   // A-row / B-col / D-col
    const int fg = lane >> 4;   // k-group (A/B), row-group (D)
    const int f4 = fj >> 2;     // feat read swizzle base: sg(g4) = (4*g4 + f4) & 7

    // ---- weight fragments: global bf16 -> registers (L1/L2-hot, shared by all blocks) ----
    const u16* w1b = wb;             // [128][64] (doubly permuted)
    const u16* w2b = wb + 128 * 64;  // [16][128]
    bf8 a1[8][2];
    #pragma unroll
    for (int m = 0; m < 8; ++m) {
        #pragma unroll
        for (int kt = 0; kt < 2; ++kt)
            a1[m][kt] = *(const bf8*)&w1b[(16 * m + fj) * 64 + 32 * kt + 8 * fg];
    }
    bf8 a2[4];
    #pragma unroll
    for (int kt = 0; kt < 4; ++kt)
        a2[kt] = *(const bf8*)&w2b[fj * 128 + 32 * kt + 8 * fg];

    __syncthreads();   // feature phase is cross-wave

    #pragma unroll
    for (int g4 = 0; g4 < 4; ++g4) {
        const int r  = wv * 64 + g4 * 16 + fj;
        const int sg = (4 * g4 + f4) & 7;
        bf8 b0 = *(const bf8*)&feat_lds[r * 64 + 8 * ((0 + fg) ^ sg)];
        bf8 b1 = *(const bf8*)&feat_lds[r * 64 + 8 * ((4 + fg) ^ sg)];

        // ---- layer 1 in two m-halves; relu+pack into lane-local words ----
        // Lane (fj,fg) physical D rows 16m+4fg+rr == true hidden 32(m>>1)+8fg+4(m&1)+rr:
        // exactly the k's this lane's L2 B-fragment needs. w[m][j] = bf16 pair
        // (hidden 32(m>>1)+8fg+4(m&1)+2j, +1).
        u32 w[8][2];
        #pragma unroll
        for (int mh = 0; mh < 2; ++mh) {
            f32x4 hc[4];
            #pragma unroll
            for (int mm = 0; mm < 4; ++mm) {
                const int m = mh * 4 + mm;
                f32x4 z = {0.f, 0.f, 0.f, 0.f};
                z = __builtin_amdgcn_mfma_f32_16x16x32_bf16(a1[m][0], b0, z, 0, 0, 0);
                hc[mm] = __builtin_amdgcn_mfma_f32_16x16x32_bf16(a1[m][1], b1, z, 0, 0, 0);
            }
            #pragma unroll
            for (int mm = 0; mm < 4; ++mm) {
                const int m = mh * 4 + mm;
                w[m][0] = pk(fmaxf(hc[mm][0], 0.f), fmaxf(hc[mm][1], 0.f));
                w[m][1] = pk(fmaxf(hc[mm][2], 0.f), fmaxf(hc[mm][3], 0.f));
            }
        }

        // ---- layer 2: B-fragment assembled from the lane's OWN words (no LDS!) ----
        // b2[kt] elements e=0..7 = hidden k = 32kt+8fg+e: e<4 -> m=2kt (pairs w[2kt][0..1]),
        // e>=4 -> m=2kt+1 (pairs w[2kt+1][0..1]).
        f32x4 uacc = {0.f, 0.f, 0.f, 0.f};
        #pragma unroll
        for (int kt = 0; kt < 4; ++kt) {
            union { u32 u[4]; bf8 v; } bb;
            bb.u[0] = w[2 * kt][0];
            bb.u[1] = w[2 * kt][1];
            bb.u[2] = w[2 * kt + 1][0];
            bb.u[3] = w[2 * kt + 1][1];
            uacc = __builtin_amdgcn_mfma_f32_16x16x32_bf16(a2[kt], bb.v, uacc, 0, 0, 0);
        }

        const int xo = wv * 64 + g4 * 16 + fj;
        float* po = out + (((size_t)(b * STATE + 4 * fg)) * HH + y) * WW + xo;
        #pragma unroll
        for (int rr = 0; rr < 4; ++rr)
            po[(size_t)rr * HW] = uacc[rr];
    }
}

extern "C" void kernel_launch(void* const* d_in, const int* in_sizes, int n_in,
                              void* d_out, int out_size, void* d_ws, size_t ws_size,
                              hipStream_t stream) {
    const float* x   = (const float*)d_in[0];
    const float* dna = (const float*)d_in[1];
    const float* w1  = (const float*)d_in[2];
    const float* w2  = (const float*)d_in[3];
    float* out = (float*)d_out;
    u16* wb = (u16*)d_ws;   // 10240 u16 = 20 KB

    prep_weights<<<dim3(40), dim3(256), 0, stream>>>(w1, w2, wb);

    const int B = in_sizes[0] / (STATE * HH * WW);   // 16
    update_net13<<<dim3(B * HH), dim3(256), 0, stream>>>(x, dna, wb, out);
}